// Round 9
// baseline (781.575 us; speedup 1.0000x reference)
//
#include <hip/hip_runtime.h>

// GNN layer: out = segment_sum(nf[src], dst) @ W.T + b
// N=50000, E=800000, D=128.
// R9: delete k_sortlocal. k_agg_linear aggregates straight from the UNSORTED
// bucket buffer into a 64-node x 128-dim fp32 LDS tile (ds_add_f32, stride-2
// = free 2-way banking), then converts + MFMAs the tile vs W. R5's failure
// mode fixed: 782 blocks x 8 waves (not 196x16), broadcast pk loads (no shfl
// chain), 8 clamp-masked gathers in flight (masked edges add 0.0f).
// 3 dispatches + tiny memset.

constexpr int NN = 50000;
constexpr int NE = 800000;
constexpr int D  = 128;

constexpr int BS  = 64;                        // nodes per bucket
constexpr int NB  = (NN + BS - 1) / BS;        // 782 buckets
constexpr int CAP = 2048;                      // cap/bucket (mean 1024, sd 32)
constexpr int EPB = 4096;                      // edges per bucket-block
constexpr int NBLK_B = (NE + EPB - 1) / EPB;   // 196 bucket blocks

constexpr int AROW = 132;                      // LDS acc row stride (floats)

typedef __attribute__((ext_vector_type(8))) short bf16x8;
typedef __attribute__((ext_vector_type(4))) float f32x4;

__device__ inline unsigned short f2bf(float f) {           // RNE
    unsigned u = __float_as_uint(f);
    return (unsigned short)((u + 0x7fffu + ((u >> 16) & 1u)) >> 16);
}
__device__ inline float bflo(unsigned v) { return __uint_as_float(v << 16); }
__device__ inline float bfhi(unsigned v) { return __uint_as_float(v & 0xffff0000u); }

// ---- 1. fused prep (nf->bf16, W->bf16) + bucket partition -----------------
constexpr int NF4 = NN * D / 4;                           // 1,600,000
constexpr int W4  = D * D / 4;                            // 4,096
constexpr int NBLK_P = (NF4 + W4 + 255) / 256;            // 6267
constexpr int GRID_A = NBLK_B + NBLK_P;

__global__ __launch_bounds__(256) void k_prep_bucket(
    const float* __restrict__ nf, const float* __restrict__ W,
    const int* __restrict__ ei,
    ushort* __restrict__ nfh, ushort* __restrict__ Wh,
    int* __restrict__ cursor, unsigned* __restrict__ buf)
{
    __shared__ int h[NB];
    __shared__ int gbase[NB];
    __shared__ int lcur[NB];
    const int t = threadIdx.x;

    if (blockIdx.x < NBLK_B) {
        // bucket branch: pk=(dst<<16)|src into exclusive dense segments
        for (int i = t; i < NB; i += 256) { h[i] = 0; lcur[i] = 0; }
        __syncthreads();
        const int e0 = blockIdx.x * EPB;
        unsigned pk[16];
        #pragma unroll
        for (int j = 0; j < 16; ++j) {
            int e = e0 + j * 256 + t;
            if (e < NE) {
                unsigned s = (unsigned)ei[e];
                unsigned d = (unsigned)ei[NE + e];
                pk[j] = (d << 16) | s;                 // bucket = pk >> 22
                atomicAdd(&h[pk[j] >> 22], 1);
            }
        }
        __syncthreads();
        for (int i = t; i < NB; i += 256)
            if (h[i] > 0) gbase[i] = i * CAP + atomicAdd(&cursor[i], h[i]);
        __syncthreads();
        #pragma unroll
        for (int j = 0; j < 16; ++j) {
            int e = e0 + j * 256 + t;
            if (e < NE) {
                unsigned b = pk[j] >> 22;
                int l = atomicAdd(&lcur[b], 1);
                buf[gbase[b] + l] = pk[j];
            }
        }
    } else {
        // prep branch: bf16 conversion
        int i = (blockIdx.x - NBLK_B) * 256 + t;
        if (i < NF4) {
            float4 v = ((const float4*)nf)[i];
            ((ushort4*)nfh)[i] = make_ushort4(f2bf(v.x), f2bf(v.y), f2bf(v.z), f2bf(v.w));
        } else if (i < NF4 + W4) {
            int k = i - NF4;
            float4 v = ((const float4*)W)[k];
            ((ushort4*)Wh)[k] = make_ushort4(f2bf(v.x), f2bf(v.y), f2bf(v.z), f2bf(v.w));
        }
    }
}

// ---- 2. fused aggregate (LDS fp32 tile) + linear (MFMA) -------------------
// One block (512 thr = 8 waves) per 64-node bucket. Waves interleave over the
// bucket's unsorted edges in batches of 8: broadcast pk load, 8 gathers in
// flight, 2 ds_add_f32 per edge per lane (stride-2 -> free 2-way banking).
// Epilogue: 4 row-tiles x 8 col-chunks; wave w owns col chunk w for all
// tiles; A-frag read from LDS fp32 (row stride 132 spreads banks) -> bf16.
__global__ __launch_bounds__(512) void k_agg_linear(
    const unsigned* __restrict__ nfh, const unsigned* __restrict__ buf,
    const int* __restrict__ cursor, const ushort* __restrict__ Wh,
    const float* __restrict__ bias, float* __restrict__ out)
{
    __shared__ float acc[BS * AROW];               // 33792 B
    const int t = threadIdx.x, lane = t & 63, w = t >> 6;
    const int b = blockIdx.x;

    for (int i = t; i < BS * AROW / 4; i += 512)
        ((float4*)acc)[i] = make_float4(0.f, 0.f, 0.f, 0.f);
    __syncthreads();

    const int cnt = cursor[b];
    const unsigned* mybuf = buf + b * CAP;
    const int lim = cnt - 1;

    for (int p0 = w * 8; p0 < cnt; p0 += 64) {     // waves interleave batches
        unsigned pk[8]; float msk[8];
        #pragma unroll
        for (int j = 0; j < 8; ++j) {
            int pos = p0 + j;
            msk[j] = (pos <= lim) ? 1.f : 0.f;
            if (pos > lim) pos = lim;              // clamp: valid, L1-warm
            pk[j] = mybuf[pos];                    // wave-uniform broadcast
        }
        unsigned v[8];
        #pragma unroll
        for (int j = 0; j < 8; ++j)
            v[j] = nfh[(size_t)(pk[j] & 0xffffu) * 64 + lane];
        #pragma unroll
        for (int j = 0; j < 8; ++j) {
            int n = (int)((pk[j] >> 16) & (BS - 1));
            float* p = acc + n * AROW + 2 * lane;
            atomicAdd(p,     msk[j] * bflo(v[j]));
            atomicAdd(p + 1, msk[j] * bfhi(v[j]));
        }
    }
    __syncthreads();

    // epilogue: tile -> bf16 A-frags -> MFMA vs W -> out
    const int m = lane & 15, q = lane >> 4;
    const int c0 = w * 16;
    const float bv = bias[c0 + m];
    const ushort* wrow = Wh + (size_t)(c0 + m) * D + q * 8;
    bf16x8 bfr[4];
    #pragma unroll
    for (int kk = 0; kk < 4; ++kk)
        bfr[kk] = *(const bf16x8*)(wrow + kk * 32);

    #pragma unroll
    for (int t16 = 0; t16 < 4; ++t16) {
        const int grow0 = b * BS + t16 * 16;
        if (grow0 >= NN) break;                    // block-uniform: safe
        const float* arow = acc + (t16 * 16 + m) * AROW + q * 8;
        f32x4 dacc = { bv, bv, bv, bv };
        #pragma unroll
        for (int kk = 0; kk < 4; ++kk) {
            float4 lo = *(const float4*)(arow + kk * 32);
            float4 hi = *(const float4*)(arow + kk * 32 + 4);
            bf16x8 af;
            af[0] = (short)f2bf(lo.x); af[1] = (short)f2bf(lo.y);
            af[2] = (short)f2bf(lo.z); af[3] = (short)f2bf(lo.w);
            af[4] = (short)f2bf(hi.x); af[5] = (short)f2bf(hi.y);
            af[6] = (short)f2bf(hi.z); af[7] = (short)f2bf(hi.w);
            dacc = __builtin_amdgcn_mfma_f32_16x16x32_bf16(af, bfr[kk], dacc, 0, 0, 0);
        }
        float* op = out + (size_t)(grow0 + q * 4) * D + c0 + m;
        op[0]     = dacc[0];
        op[D]     = dacc[1];
        op[2 * D] = dacc[2];
        op[3 * D] = dacc[3];
    }
}

extern "C" void kernel_launch(void* const* d_in, const int* in_sizes, int n_in,
                              void* d_out, int out_size, void* d_ws, size_t ws_size,
                              hipStream_t stream) {
    const float* nf = (const float*)d_in[0];
    const int*   ei = (const int*)d_in[1];
    const float* W  = (const float*)d_in[2];
    const float* b  = (const float*)d_in[3];
    float* out = (float*)d_out;

    // workspace (~19.3 MB; >=29.4 MB proven available in R4)
    ushort*   nfh    = (ushort*)d_ws;                  // NN*D bf16 = 12.8 MB
    ushort*   Wh     = nfh + (size_t)NN * D;           // 32 KB
    unsigned* buf    = (unsigned*)(Wh + D * D);        // NB*CAP u32 = 6.4 MB
    int*      cursor = (int*)(buf + (size_t)NB * CAP); // NB ints

    hipMemsetAsync(cursor, 0, NB * sizeof(int), stream);
    k_prep_bucket<<<GRID_A, 256, 0, stream>>>(nf, W, ei, nfh, Wh, cursor, buf);
    k_agg_linear <<<NB, 512, 0, stream>>>((const unsigned*)nfh, buf, cursor, Wh, b, out);
}

// Round 10
// 145.795 us; speedup vs baseline: 5.3608x; 5.3608x over previous
//
#include <hip/hip_runtime.h>

// GNN layer: out = segment_sum(nf[src], dst) @ W.T + b
// N=50000, E=800000, D=128.
// R10: R9's block-LDS-atomic aggregate confirmed the R5 law (LDS-atomic +
// few waves = ~700us; register accum + 50k waves = ~46us). Revert to R8's
// agg, and fuse sortlocal INTO it: block = one 128-node bucket (1024 thr,
// 16 waves); Phase A sorts bucket edges into LDS srt (8KB, no global
// round-trip, one less dispatch ~10us + kernel ~10us); Phase B = R8 gather
// (8 nodes/wave sequential, 8 clamp-batched loads in flight, cndmask tail);
// Phase C = 64 MFMA tile-tasks over 16 waves. 3 dispatches.

constexpr int NN = 50000;
constexpr int NE = 800000;
constexpr int D  = 128;

constexpr int BS  = 128;                       // nodes per bucket
constexpr int NB  = (NN + BS - 1) / BS;        // 391 buckets
constexpr int CAP = 4096;                      // cap/bucket (mean 2048, sd 45)
constexpr int EPB = 4096;                      // edges per bucket-block
constexpr int NBLK_B = (NE + EPB - 1) / EPB;   // 196 bucket blocks

constexpr int AROWU = 136;                     // tile row stride (ushorts)

typedef __attribute__((ext_vector_type(8))) short bf16x8;
typedef __attribute__((ext_vector_type(4))) float f32x4;

__device__ inline unsigned short f2bf(float f) {           // RNE
    unsigned u = __float_as_uint(f);
    return (unsigned short)((u + 0x7fffu + ((u >> 16) & 1u)) >> 16);
}
__device__ inline float bflo(unsigned v) { return __uint_as_float(v << 16); }
__device__ inline float bfhi(unsigned v) { return __uint_as_float(v & 0xffff0000u); }

// ---- 1. fused prep (nf->bf16, W->bf16) + bucket partition (R8-verified) ---
constexpr int NF4 = NN * D / 4;                           // 1,600,000
constexpr int W4  = D * D / 4;                            // 4,096
constexpr int NBLK_P = (NF4 + W4 + 255) / 256;            // 6267
constexpr int GRID_A = NBLK_B + NBLK_P;

__global__ __launch_bounds__(256) void k_prep_bucket(
    const float* __restrict__ nf, const float* __restrict__ W,
    const int* __restrict__ ei,
    ushort* __restrict__ nfh, ushort* __restrict__ Wh,
    int* __restrict__ cursor, unsigned* __restrict__ buf)
{
    __shared__ int h[NB];
    __shared__ int gbase[NB];
    __shared__ int lcur[NB];
    const int t = threadIdx.x;

    if (blockIdx.x < NBLK_B) {
        // bucket branch: pk=(dst<<16)|src into exclusive dense segments
        for (int i = t; i < NB; i += 256) { h[i] = 0; lcur[i] = 0; }
        __syncthreads();
        const int e0 = blockIdx.x * EPB;
        unsigned pk[16];
        #pragma unroll
        for (int j = 0; j < 16; ++j) {
            int e = e0 + j * 256 + t;
            if (e < NE) {
                unsigned s = (unsigned)ei[e];
                unsigned d = (unsigned)ei[NE + e];
                pk[j] = (d << 16) | s;                 // bucket = pk >> 23
                atomicAdd(&h[pk[j] >> 23], 1);
            }
        }
        __syncthreads();
        for (int i = t; i < NB; i += 256)
            if (h[i] > 0) gbase[i] = i * CAP + atomicAdd(&cursor[i], h[i]);
        __syncthreads();
        #pragma unroll
        for (int j = 0; j < 16; ++j) {
            int e = e0 + j * 256 + t;
            if (e < NE) {
                unsigned b = pk[j] >> 23;
                int l = atomicAdd(&lcur[b], 1);
                buf[gbase[b] + l] = pk[j];
            }
        }
    } else {
        // prep branch: bf16 conversion
        int i = (blockIdx.x - NBLK_B) * 256 + t;
        if (i < NF4) {
            float4 v = ((const float4*)nf)[i];
            ((ushort4*)nfh)[i] = make_ushort4(f2bf(v.x), f2bf(v.y), f2bf(v.z), f2bf(v.w));
        } else if (i < NF4 + W4) {
            int k = i - NF4;
            float4 v = ((const float4*)W)[k];
            ((ushort4*)Wh)[k] = make_ushort4(f2bf(v.x), f2bf(v.y), f2bf(v.z), f2bf(v.w));
        }
    }
}

// ---- 2. fused sort + aggregate + linear -----------------------------------
// One block (1024 thr = 16 waves) per 128-node bucket.
// A: LDS counting-sort of the bucket's ~2048 edges (srt = local CSR, 8KB).
// B: wave w aggregates nodes w*8..w*8+7 (register accum, 8 loads in flight).
// C: 64 tasks = 8 row-tiles x 8 col-chunks; wave w does tasks w+16i.
__global__ __launch_bounds__(1024) void k_sort_agg(
    const unsigned* __restrict__ nfh, const unsigned* __restrict__ buf,
    const int* __restrict__ cursor, const ushort* __restrict__ Wh,
    const float* __restrict__ bias, float* __restrict__ out)
{
    __shared__ ushort srt[CAP];                     // 8192 B
    __shared__ int hist[BS], off[BS], cur[BS];      // 1536 B
    __shared__ unsigned tile[BS * AROWU / 2];       // 34816 B
    const int b = blockIdx.x, t = threadIdx.x;
    const int lane = t & 63, w = t >> 6;

    int cnt = cursor[b]; if (cnt > CAP) cnt = CAP;  // defensive
    const unsigned* mybuf = buf + (size_t)b * CAP;

    // --- Phase A: hist -> scan -> scatter into LDS srt
    if (t < BS) hist[t] = 0;
    __syncthreads();
    for (int e = t; e < cnt; e += 1024)
        atomicAdd(&hist[(mybuf[e] >> 16) & (BS - 1)], 1);
    __syncthreads();
    if (t < BS) off[t] = hist[t];
    __syncthreads();
    for (int o = 1; o < BS; o <<= 1) {              // inclusive scan
        int v = (t >= o && t < BS) ? off[t - o] : 0;
        __syncthreads();
        if (t < BS) off[t] += v;
        __syncthreads();
    }
    if (t < BS) { int ex = off[t] - hist[t]; off[t] = ex; cur[t] = ex; }
    __syncthreads();
    for (int e = t; e < cnt; e += 1024) {           // buf re-read: L2-hot
        unsigned pk = mybuf[e];
        int n = (pk >> 16) & (BS - 1);
        int p = atomicAdd(&cur[n], 1);
        srt[p] = (ushort)(pk & 0xffffu);
    }
    __syncthreads();

    // --- Phase B: register aggregation, 8 nodes per wave
    #pragma unroll
    for (int i = 0; i < 8; ++i) {
        const int n = w * 8 + i;
        const int beg = off[n], e = beg + hist[n];
        float ax=0.f, ay=0.f, bx=0.f, by=0.f, cx=0.f, cy=0.f, dx=0.f, dy=0.f;
        for (int p = beg; p < e; p += 8) {
            const int lim = e - 1;
            unsigned v[8];
            #pragma unroll
            for (int j = 0; j < 8; ++j) {
                int pos = p + j;
                bool ok = pos <= lim;
                if (!ok) pos = lim;                 // clamp (valid, L1-warm)
                unsigned s = srt[pos];              // uniform ds_read: broadcast
                unsigned val = nfh[(size_t)s * 64 + lane];
                v[j] = ok ? val : 0u;               // cndmask, no float mul
            }
            ax += bflo(v[0]); ay += bfhi(v[0]);
            bx += bflo(v[1]); by += bfhi(v[1]);
            cx += bflo(v[2]); cy += bfhi(v[2]);
            dx += bflo(v[3]); dy += bfhi(v[3]);
            ax += bflo(v[4]); ay += bfhi(v[4]);
            bx += bflo(v[5]); by += bfhi(v[5]);
            cx += bflo(v[6]); cy += bfhi(v[6]);
            dx += bflo(v[7]); dy += bfhi(v[7]);
        }
        float rx = (ax + bx) + (cx + dx);
        float ry = (ay + by) + (cy + dy);
        tile[n * (AROWU / 2) + lane] =
            (unsigned)f2bf(rx) | ((unsigned)f2bf(ry) << 16);
    }
    __syncthreads();

    // --- Phase C: 8 tiles x 8 col-chunks = 64 MFMA tasks over 16 waves
    const int m = lane & 15, q = lane >> 4;
    const ushort* lds = (const ushort*)tile;
    #pragma unroll
    for (int i = 0; i < 4; ++i) {
        const int task = w + 16 * i;                // 0..63, bijective
        const int t16  = task >> 3;                 // row-tile 0..7
        const int c0   = (task & 7) * 16;           // col chunk
        const int grow0 = b * BS + t16 * 16;
        if (grow0 < NN) {                           // last bucket: 5 full tiles
            bf16x8 a[4];
            const ushort* arow = lds + (t16 * 16 + m) * AROWU + q * 8;
            #pragma unroll
            for (int kk = 0; kk < 4; ++kk)
                a[kk] = *(const bf16x8*)(arow + kk * 32);
            float bv = bias[c0 + m];
            f32x4 acc = { bv, bv, bv, bv };
            const ushort* wrow = Wh + (size_t)(c0 + m) * D + q * 8;
            #pragma unroll
            for (int kk = 0; kk < 4; ++kk) {
                bf16x8 bb = *(const bf16x8*)(wrow + kk * 32);
                acc = __builtin_amdgcn_mfma_f32_16x16x32_bf16(a[kk], bb, acc, 0, 0, 0);
            }
            float* op = out + (size_t)(grow0 + q * 4) * D + c0 + m;
            op[0]     = acc[0];
            op[D]     = acc[1];
            op[2 * D] = acc[2];
            op[3 * D] = acc[3];
        }
    }
}

extern "C" void kernel_launch(void* const* d_in, const int* in_sizes, int n_in,
                              void* d_out, int out_size, void* d_ws, size_t ws_size,
                              hipStream_t stream) {
    const float* nf = (const float*)d_in[0];
    const int*   ei = (const int*)d_in[1];
    const float* W  = (const float*)d_in[2];
    const float* b  = (const float*)d_in[3];
    float* out = (float*)d_out;

    // workspace (~19.3 MB; >=29.4 MB proven available in R4)
    ushort*   nfh    = (ushort*)d_ws;                  // NN*D bf16 = 12.8 MB
    ushort*   Wh     = nfh + (size_t)NN * D;           // 32 KB
    unsigned* buf    = (unsigned*)(Wh + D * D);        // NB*CAP u32 = 6.4 MB
    int*      cursor = (int*)(buf + (size_t)NB * CAP); // NB ints

    hipMemsetAsync(cursor, 0, NB * sizeof(int), stream);
    k_prep_bucket<<<GRID_A, 256, 0, stream>>>(nf, W, ei, nfh, Wh, cursor, buf);
    k_sort_agg   <<<NB, 1024, 0, stream>>>((const unsigned*)nfh, buf, cursor, Wh, b, out);
}

// Round 11
// 140.657 us; speedup vs baseline: 5.5566x; 1.0365x over previous
//
#include <hip/hip_runtime.h>

// GNN layer: out = segment_sum(nf[src], dst) @ W.T + b
// N=50000, E=800000, D=128.
// R11: deterministic bucket build. Each (bucket, edge-block) pair owns a
// fixed 32-edge sub-segment of buf -> no global cursor, no memset, no hist
// pre-pass; prep_bucket's bucket branch is one pass (load -> LDS count ->
// write run). k_sort_agg phase A: scan the 391 per-block counts, binary-
// search copy sub-segments into LDS, then node-sort (R10's phase A source
// moved from global to LDS). Phases B (8 nodes/wave register aggregate,
// 8 loads in flight) and C (64 MFMA tasks) unchanged from R10.
// 2 dispatches total (was 3 + memset).

constexpr int NN = 50000;
constexpr int NE = 800000;
constexpr int D  = 128;

constexpr int BS   = 128;                      // nodes per bucket
constexpr int NB   = (NN + BS - 1) / BS;       // 391 buckets
constexpr int EPB  = 2048;                     // edges per bucket-block
constexpr int NSB  = (NE + EPB - 1) / EPB;     // 391 bucket-blocks
constexpr int SUBCAP = 32;                     // edges per (bucket,block) cell
                                               // Poisson(5.24): P(>32)~1e-11
constexpr int CAP  = 4096;                     // per-bucket LDS edge cap

constexpr int AROWU = 136;                     // tile row stride (ushorts)

typedef __attribute__((ext_vector_type(8))) short bf16x8;
typedef __attribute__((ext_vector_type(4))) float f32x4;

__device__ inline unsigned short f2bf(float f) {           // RNE
    unsigned u = __float_as_uint(f);
    return (unsigned short)((u + 0x7fffu + ((u >> 16) & 1u)) >> 16);
}
__device__ inline float bflo(unsigned v) { return __uint_as_float(v << 16); }
__device__ inline float bfhi(unsigned v) { return __uint_as_float(v & 0xffff0000u); }

// ---- 1. fused prep (nf->bf16, W->bf16) + deterministic bucket partition ---
constexpr int NF4 = NN * D / 4;                           // 1,600,000
constexpr int W4  = D * D / 4;                            // 4,096
constexpr int NBLK_P = (NF4 + W4 + 255) / 256;            // 6267
constexpr int GRID_A = NSB + NBLK_P;

__global__ __launch_bounds__(256) void k_prep_bucket(
    const float* __restrict__ nf, const float* __restrict__ W,
    const int* __restrict__ ei,
    ushort* __restrict__ nfh, ushort* __restrict__ Wh,
    ushort* __restrict__ cnt, unsigned* __restrict__ buf)
{
    __shared__ int lcur[NB];
    const int t = threadIdx.x;

    if (blockIdx.x < NSB) {
        // bucket branch: one pass, fixed sub-segment per (bucket, block)
        const int blk = blockIdx.x;
        for (int i = t; i < NB; i += 256) lcur[i] = 0;
        __syncthreads();
        const int e0 = blk * EPB;
        #pragma unroll
        for (int j = 0; j < 8; ++j) {
            int e = e0 + j * 256 + t;
            if (e < NE) {
                unsigned s = (unsigned)ei[e];
                unsigned d = (unsigned)ei[NE + e];
                unsigned pk = (d << 16) | s;           // bucket = pk >> 23
                int bk = pk >> 23;
                int l = atomicAdd(&lcur[bk], 1);
                if (l < SUBCAP)                        // P(overflow) ~1e-11
                    buf[((size_t)bk * NSB + blk) * SUBCAP + l] = pk;
            }
        }
        __syncthreads();
        for (int i = t; i < NB; i += 256)              // coalesced 782B write
            cnt[blk * NB + i] = (ushort)(lcur[i] < SUBCAP ? lcur[i] : SUBCAP);
    } else {
        // prep branch: bf16 conversion
        int i = (blockIdx.x - NSB) * 256 + t;
        if (i < NF4) {
            float4 v = ((const float4*)nf)[i];
            ((ushort4*)nfh)[i] = make_ushort4(f2bf(v.x), f2bf(v.y), f2bf(v.z), f2bf(v.w));
        } else if (i < NF4 + W4) {
            int k = i - NF4;
            float4 v = ((const float4*)W)[k];
            ((ushort4*)Wh)[k] = make_ushort4(f2bf(v.x), f2bf(v.y), f2bf(v.z), f2bf(v.w));
        }
    }
}

// ---- 2. fused gather-sort + aggregate + linear ----------------------------
// One block (1024 thr = 16 waves) per 128-node bucket.
// A: scan 391 sub-counts, copy sub-segments into LDS (binary search on the
//    inclusive scan), node-hist, scatter into LDS srt (local CSR).
// B: wave w aggregates nodes w*8..w*8+7 (register accum, 8 loads in flight).
// C: 64 tasks = 8 row-tiles x 8 col-chunks; wave w does tasks w+16i.
__global__ __launch_bounds__(1024) void k_sort_agg(
    const unsigned* __restrict__ nfh, const unsigned* __restrict__ buf,
    const ushort* __restrict__ cnt, const ushort* __restrict__ Wh,
    const float* __restrict__ bias, float* __restrict__ out)
{
    __shared__ unsigned pkbuf[CAP];                 // 16384 B
    __shared__ ushort srt[CAP];                     // 8192 B
    __shared__ int scnt[512];                       // 2048 B (inclusive scan)
    __shared__ int sbase[NSB];                      // 1564 B
    __shared__ int hist[BS], off[BS], cur[BS];      // 1536 B
    __shared__ unsigned tile[BS * AROWU / 2];       // 34816 B  (total ~64.5KB)
    const int b = blockIdx.x, t = threadIdx.x;
    const int lane = t & 63, w = t >> 6;

    // --- Phase A1: per-sub-block counts -> inclusive scan -> bases
    int my = 0;
    if (t < NSB) my = (int)cnt[t * NB + b];
    if (t < 512) scnt[t] = (t < NSB) ? my : 0;
    __syncthreads();
    for (int o = 1; o < 512; o <<= 1) {
        int v = (t >= o && t < 512) ? scnt[t - o] : 0;
        __syncthreads();
        if (t < 512) scnt[t] += v;
        __syncthreads();
    }
    if (t < NSB) sbase[t] = scnt[t] - my;
    if (t < BS) hist[t] = 0;
    __syncthreads();
    int total = scnt[NSB - 1];
    if (total > CAP) total = CAP;                  // defensive

    // --- Phase A2: gather sub-segments into LDS + node histogram
    for (int p = t; p < total; p += 1024) {
        int lo = 0, hi = NSB - 1;                  // min i: scnt[i] > p
        while (lo < hi) {
            int mid = (lo + hi) >> 1;
            if (scnt[mid] > p) hi = mid; else lo = mid + 1;
        }
        unsigned pk = buf[((size_t)b * NSB + lo) * SUBCAP + (p - sbase[lo])];
        pkbuf[p] = pk;
        atomicAdd(&hist[(pk >> 16) & (BS - 1)], 1);
    }
    __syncthreads();

    // --- Phase A3: node scan + scatter into srt (local CSR)
    if (t < BS) off[t] = hist[t];
    __syncthreads();
    for (int o = 1; o < BS; o <<= 1) {
        int v = (t >= o && t < BS) ? off[t - o] : 0;
        __syncthreads();
        if (t < BS) off[t] += v;
        __syncthreads();
    }
    if (t < BS) { int ex = off[t] - hist[t]; off[t] = ex; cur[t] = ex; }
    __syncthreads();
    for (int e = t; e < total; e += 1024) {
        unsigned pk = pkbuf[e];
        int n = (pk >> 16) & (BS - 1);
        int p = atomicAdd(&cur[n], 1);
        srt[p] = (ushort)(pk & 0xffffu);
    }
    __syncthreads();

    // --- Phase B: register aggregation, 8 nodes per wave
    #pragma unroll
    for (int i = 0; i < 8; ++i) {
        const int n = w * 8 + i;
        const int beg = off[n], e = beg + hist[n];
        float ax=0.f, ay=0.f, bx=0.f, by=0.f, cx=0.f, cy=0.f, dx=0.f, dy=0.f;
        for (int p = beg; p < e; p += 8) {
            const int lim = e - 1;
            unsigned v[8];
            #pragma unroll
            for (int j = 0; j < 8; ++j) {
                int pos = p + j;
                bool ok = pos <= lim;
                if (!ok) pos = lim;                 // clamp (valid, L1-warm)
                unsigned s = srt[pos];              // uniform ds_read: broadcast
                unsigned val = nfh[(size_t)s * 64 + lane];
                v[j] = ok ? val : 0u;               // cndmask, no float mul
            }
            ax += bflo(v[0]); ay += bfhi(v[0]);
            bx += bflo(v[1]); by += bfhi(v[1]);
            cx += bflo(v[2]); cy += bfhi(v[2]);
            dx += bflo(v[3]); dy += bfhi(v[3]);
            ax += bflo(v[4]); ay += bfhi(v[4]);
            bx += bflo(v[5]); by += bfhi(v[5]);
            cx += bflo(v[6]); cy += bfhi(v[6]);
            dx += bflo(v[7]); dy += bfhi(v[7]);
        }
        float rx = (ax + bx) + (cx + dx);
        float ry = (ay + by) + (cy + dy);
        tile[n * (AROWU / 2) + lane] =
            (unsigned)f2bf(rx) | ((unsigned)f2bf(ry) << 16);
    }
    __syncthreads();

    // --- Phase C: 8 tiles x 8 col-chunks = 64 MFMA tasks over 16 waves
    const int m = lane & 15, q = lane >> 4;
    const ushort* lds = (const ushort*)tile;
    #pragma unroll
    for (int i = 0; i < 4; ++i) {
        const int task = w + 16 * i;                // 0..63, bijective
        const int t16  = task >> 3;                 // row-tile 0..7
        const int c0   = (task & 7) * 16;           // col chunk
        const int grow0 = b * BS + t16 * 16;
        if (grow0 < NN) {                           // last bucket: 5 full tiles
            bf16x8 a[4];
            const ushort* arow = lds + (t16 * 16 + m) * AROWU + q * 8;
            #pragma unroll
            for (int kk = 0; kk < 4; ++kk)
                a[kk] = *(const bf16x8*)(arow + kk * 32);
            float bv = bias[c0 + m];
            f32x4 acc = { bv, bv, bv, bv };
            const ushort* wrow = Wh + (size_t)(c0 + m) * D + q * 8;
            #pragma unroll
            for (int kk = 0; kk < 4; ++kk) {
                bf16x8 bb = *(const bf16x8*)(wrow + kk * 32);
                acc = __builtin_amdgcn_mfma_f32_16x16x32_bf16(a[kk], bb, acc, 0, 0, 0);
            }
            float* op = out + (size_t)(grow0 + q * 4) * D + c0 + m;
            op[0]     = acc[0];
            op[D]     = acc[1];
            op[2 * D] = acc[2];
            op[3 * D] = acc[3];
        }
    }
}

extern "C" void kernel_launch(void* const* d_in, const int* in_sizes, int n_in,
                              void* d_out, int out_size, void* d_ws, size_t ws_size,
                              hipStream_t stream) {
    const float* nf = (const float*)d_in[0];
    const int*   ei = (const int*)d_in[1];
    const float* W  = (const float*)d_in[2];
    const float* b  = (const float*)d_in[3];
    float* out = (float*)d_out;

    // workspace (~33 MB; ws is ~256 MB per R6's poison-fill counter)
    ushort*   nfh = (ushort*)d_ws;                     // NN*D bf16 = 12.8 MB
    ushort*   Wh  = nfh + (size_t)NN * D;              // 32 KB
    unsigned* buf = (unsigned*)(Wh + D * D);           // NB*NSB*SUBCAP u32 = 19.6 MB
    ushort*   cnt = (ushort*)(buf + (size_t)NB * NSB * SUBCAP);  // 306 KB

    k_prep_bucket<<<GRID_A, 256, 0, stream>>>(nf, W, ei, nfh, Wh, cnt, buf);
    k_sort_agg   <<<NB, 1024, 0, stream>>>((const unsigned*)nfh, buf, cnt, Wh, b, out);
}

// Round 12
// 136.356 us; speedup vs baseline: 5.7319x; 1.0315x over previous
//
#include <hip/hip_runtime.h>

// GNN layer: out = segment_sum(nf[src], dst) @ W.T + b
// N=50000, E=800000, D=128.
// R12: kill the last random global scatter (since R4, ~55-65us wherever it
// lived). prep's bucket branch now LDS-counting-sorts its 4096 edges by
// bucket, then writes ONE dense coalesced 16KB run + a 392-ushort offset
// row. buf: 19.6MB sparse -> 3.2MB dense (L2-resident for the consumer).
// k_sort_agg: R11 structure; phase A sources runs from dense regions via
// per-block offsets. 2 dispatches, no memset, deterministic.

constexpr int NN = 50000;
constexpr int NE = 800000;
constexpr int D  = 128;

constexpr int BS   = 128;                      // nodes per bucket
constexpr int NB   = (NN + BS - 1) / BS;       // 391 buckets
constexpr int EPB  = 4096;                     // edges per producer block
constexpr int NSB  = (NE + EPB - 1) / EPB;     // 196 producer blocks
constexpr int CAP  = 4096;                     // per-bucket LDS edge cap (45 sigma)

constexpr int AROWU = 136;                     // tile row stride (ushorts)

typedef __attribute__((ext_vector_type(8))) short bf16x8;
typedef __attribute__((ext_vector_type(4))) float f32x4;

__device__ inline unsigned short f2bf(float f) {           // RNE
    unsigned u = __float_as_uint(f);
    return (unsigned short)((u + 0x7fffu + ((u >> 16) & 1u)) >> 16);
}
__device__ inline float bflo(unsigned v) { return __uint_as_float(v << 16); }
__device__ inline float bfhi(unsigned v) { return __uint_as_float(v & 0xffff0000u); }

// ---- 1. fused prep (bf16 cvt) + bucket-sort partition (coalesced out) -----
constexpr int NF4 = NN * D / 4;                           // 1,600,000
constexpr int W4  = D * D / 4;                            // 4,096
constexpr int NBLK_P = (NF4 + W4 + 511) / 512;            // 3134
constexpr int GRID_A = NSB + NBLK_P;

__global__ __launch_bounds__(512) void k_prep_bucket(
    const float* __restrict__ nf, const float* __restrict__ W,
    const int* __restrict__ ei,
    ushort* __restrict__ nfh, ushort* __restrict__ Wh,
    ushort* __restrict__ offs, unsigned* __restrict__ buf)
{
    __shared__ int hist[NB], off[NB], cur[NB];     // 4692 B
    __shared__ unsigned spk[EPB];                  // 16384 B
    const int t = threadIdx.x;

    if (blockIdx.x < NSB) {
        const int blk = blockIdx.x;
        const int e0  = blk * EPB;
        int cnt = NE - e0; if (cnt > EPB) cnt = EPB;

        for (int i = t; i < NB; i += 512) hist[i] = 0;
        __syncthreads();

        unsigned pk[8];
        #pragma unroll
        for (int j = 0; j < 8; ++j) {
            int idx = j * 512 + t;
            if (idx < cnt) {
                int e = e0 + idx;
                unsigned s = (unsigned)ei[e];
                unsigned d = (unsigned)ei[NE + e];
                pk[j] = (d << 16) | s;             // bucket = pk >> 23
                atomicAdd(&hist[pk[j] >> 23], 1);
            }
        }
        __syncthreads();
        if (t < NB) off[t] = hist[t];
        __syncthreads();
        for (int o = 1; o < NB; o <<= 1) {         // inclusive scan over 391
            int v = (t >= o && t < NB) ? off[t - o] : 0;
            __syncthreads();
            if (t < NB) off[t] += v;
            __syncthreads();
        }
        if (t < NB) {
            int ex = off[t] - hist[t];
            cur[t] = ex;
            offs[blk * (NB + 1) + t] = (ushort)ex; // coalesced ushort row
        }
        if (t == 0) offs[blk * (NB + 1) + NB] = (ushort)cnt;
        __syncthreads();
        #pragma unroll
        for (int j = 0; j < 8; ++j) {
            int idx = j * 512 + t;
            if (idx < cnt) {
                int l = atomicAdd(&cur[pk[j] >> 23], 1);
                spk[l] = pk[j];
            }
        }
        __syncthreads();
        for (int i = t; i < cnt; i += 512)         // dense coalesced 16KB
            buf[(size_t)blk * EPB + i] = spk[i];
    } else {
        // prep branch: bf16 conversion
        int i = (blockIdx.x - NSB) * 512 + t;
        if (i < NF4) {
            float4 v = ((const float4*)nf)[i];
            ((ushort4*)nfh)[i] = make_ushort4(f2bf(v.x), f2bf(v.y), f2bf(v.z), f2bf(v.w));
        } else if (i < NF4 + W4) {
            int k = i - NF4;
            float4 v = ((const float4*)W)[k];
            ((ushort4*)Wh)[k] = make_ushort4(f2bf(v.x), f2bf(v.y), f2bf(v.z), f2bf(v.w));
        }
    }
}

// ---- 2. fused gather-sort + aggregate + linear ----------------------------
// One block (1024 thr = 16 waves) per 128-node bucket.
// A: read per-producer run offsets, scan 196 counts, binary-search copy the
//    runs into LDS, node-hist, scatter into LDS srt (local CSR).
// B: wave w aggregates nodes w*8..w*8+7 (register accum, 8 loads in flight).
// C: 64 tasks = 8 row-tiles x 8 col-chunks; wave w does tasks w+16i.
__global__ __launch_bounds__(1024) void k_sort_agg(
    const unsigned* __restrict__ nfh, const unsigned* __restrict__ buf,
    const ushort* __restrict__ offs, const ushort* __restrict__ Wh,
    const float* __restrict__ bias, float* __restrict__ out)
{
    __shared__ unsigned pkbuf[CAP];                 // 16384 B
    __shared__ ushort srt[CAP];                     // 8192 B
    __shared__ int scnt[256];                       // 1024 B (inclusive scan)
    __shared__ int sbase[NSB], rbase[NSB];          // 1568 B
    __shared__ int hist[BS], off[BS], cur[BS];      // 1536 B
    __shared__ unsigned tile[BS * AROWU / 2];       // 34816 B  (~63.5 KB)
    const int b = blockIdx.x, t = threadIdx.x;
    const int lane = t & 63, w = t >> 6;

    // --- Phase A1: per-producer run bases/counts -> inclusive scan
    int my = 0;
    if (t < NSB) {
        int o0 = (int)offs[t * (NB + 1) + b];
        int o1 = (int)offs[t * (NB + 1) + b + 1];
        rbase[t] = o0;
        my = o1 - o0;
    }
    if (t < 256) scnt[t] = (t < NSB) ? my : 0;
    if (t < BS) hist[t] = 0;
    __syncthreads();
    for (int o = 1; o < 256; o <<= 1) {
        int v = (t >= o && t < 256) ? scnt[t - o] : 0;
        __syncthreads();
        if (t < 256) scnt[t] += v;
        __syncthreads();
    }
    if (t < NSB) sbase[t] = scnt[t] - my;
    __syncthreads();
    int total = scnt[NSB - 1];
    if (total > CAP) total = CAP;                  // defensive

    // --- Phase A2: copy runs into LDS + node histogram
    for (int p = t; p < total; p += 1024) {
        int lo = 0, hi = NSB - 1;                  // min i: scnt[i] > p
        while (lo < hi) {
            int mid = (lo + hi) >> 1;
            if (scnt[mid] > p) hi = mid; else lo = mid + 1;
        }
        unsigned pk = buf[(size_t)lo * EPB + rbase[lo] + (p - sbase[lo])];
        pkbuf[p] = pk;
        atomicAdd(&hist[(pk >> 16) & (BS - 1)], 1);
    }
    __syncthreads();

    // --- Phase A3: node scan + scatter into srt (local CSR)
    if (t < BS) off[t] = hist[t];
    __syncthreads();
    for (int o = 1; o < BS; o <<= 1) {
        int v = (t >= o && t < BS) ? off[t - o] : 0;
        __syncthreads();
        if (t < BS) off[t] += v;
        __syncthreads();
    }
    if (t < BS) { int ex = off[t] - hist[t]; off[t] = ex; cur[t] = ex; }
    __syncthreads();
    for (int e = t; e < total; e += 1024) {
        unsigned pk = pkbuf[e];
        int n = (pk >> 16) & (BS - 1);
        int p = atomicAdd(&cur[n], 1);
        srt[p] = (ushort)(pk & 0xffffu);
    }
    __syncthreads();

    // --- Phase B: register aggregation, 8 nodes per wave
    #pragma unroll
    for (int i = 0; i < 8; ++i) {
        const int n = w * 8 + i;
        const int beg = off[n], e = beg + hist[n];
        float ax=0.f, ay=0.f, bx=0.f, by=0.f, cx=0.f, cy=0.f, dx=0.f, dy=0.f;
        for (int p = beg; p < e; p += 8) {
            const int lim = e - 1;
            unsigned v[8];
            #pragma unroll
            for (int j = 0; j < 8; ++j) {
                int pos = p + j;
                bool ok = pos <= lim;
                if (!ok) pos = lim;                 // clamp (valid, L1-warm)
                unsigned s = srt[pos];              // uniform ds_read: broadcast
                unsigned val = nfh[(size_t)s * 64 + lane];
                v[j] = ok ? val : 0u;               // cndmask, no float mul
            }
            ax += bflo(v[0]); ay += bfhi(v[0]);
            bx += bflo(v[1]); by += bfhi(v[1]);
            cx += bflo(v[2]); cy += bfhi(v[2]);
            dx += bflo(v[3]); dy += bfhi(v[3]);
            ax += bflo(v[4]); ay += bfhi(v[4]);
            bx += bflo(v[5]); by += bfhi(v[5]);
            cx += bflo(v[6]); cy += bfhi(v[6]);
            dx += bflo(v[7]); dy += bfhi(v[7]);
        }
        float rx = (ax + bx) + (cx + dx);
        float ry = (ay + by) + (cy + dy);
        tile[n * (AROWU / 2) + lane] =
            (unsigned)f2bf(rx) | ((unsigned)f2bf(ry) << 16);
    }
    __syncthreads();

    // --- Phase C: 8 tiles x 8 col-chunks = 64 MFMA tasks over 16 waves
    const int m = lane & 15, q = lane >> 4;
    const ushort* lds = (const ushort*)tile;
    #pragma unroll
    for (int i = 0; i < 4; ++i) {
        const int task = w + 16 * i;                // 0..63, bijective
        const int t16  = task >> 3;                 // row-tile 0..7
        const int c0   = (task & 7) * 16;           // col chunk
        const int grow0 = b * BS + t16 * 16;
        if (grow0 < NN) {                           // last bucket: 5 full tiles
            bf16x8 a[4];
            const ushort* arow = lds + (t16 * 16 + m) * AROWU + q * 8;
            #pragma unroll
            for (int kk = 0; kk < 4; ++kk)
                a[kk] = *(const bf16x8*)(arow + kk * 32);
            float bv = bias[c0 + m];
            f32x4 acc = { bv, bv, bv, bv };
            const ushort* wrow = Wh + (size_t)(c0 + m) * D + q * 8;
            #pragma unroll
            for (int kk = 0; kk < 4; ++kk) {
                bf16x8 bb = *(const bf16x8*)(wrow + kk * 32);
                acc = __builtin_amdgcn_mfma_f32_16x16x32_bf16(a[kk], bb, acc, 0, 0, 0);
            }
            float* op = out + (size_t)(grow0 + q * 4) * D + c0 + m;
            op[0]     = acc[0];
            op[D]     = acc[1];
            op[2 * D] = acc[2];
            op[3 * D] = acc[3];
        }
    }
}

extern "C" void kernel_launch(void* const* d_in, const int* in_sizes, int n_in,
                              void* d_out, int out_size, void* d_ws, size_t ws_size,
                              hipStream_t stream) {
    const float* nf = (const float*)d_in[0];
    const int*   ei = (const int*)d_in[1];
    const float* W  = (const float*)d_in[2];
    const float* b  = (const float*)d_in[3];
    float* out = (float*)d_out;

    // workspace (~16.2 MB)
    ushort*   nfh  = (ushort*)d_ws;                    // NN*D bf16 = 12.8 MB
    ushort*   Wh   = nfh + (size_t)NN * D;             // 32 KB
    unsigned* buf  = (unsigned*)(Wh + D * D);          // NSB*EPB u32 = 3.2 MB
    ushort*   offs = (ushort*)(buf + (size_t)NSB * EPB); // NSB*(NB+1) = 154 KB

    k_prep_bucket<<<GRID_A, 512, 0, stream>>>(nf, W, ei, nfh, Wh, offs, buf);
    k_sort_agg   <<<NB, 1024, 0, stream>>>((const unsigned*)nfh, buf, offs, Wh, b, out);
}

// Round 13
// 134.011 us; speedup vs baseline: 5.8322x; 1.0175x over previous
//
#include <hip/hip_runtime.h>

// GNN layer: out = segment_sum(nf[src], dst) @ W.T + b
// N=50000, E=800000, D=128.
// R13: Phase-B gather re-vectorized. Was: 1 global_load_dword per EDGE
// (64 lanes x 4B = one row) -> VMEM-issue bound (~16cyc/instr, ~20us/CU
// budget). Now: global_load_dwordx4, 16 lanes per row, 4 EDGES per
// instruction (quarter q=lane>>4 owns edge p+4j+q, lane covers 8 dims);
// VMEM + srt-LDS reads /4, 64 lines in flight per wave. Node end: butterfly
// __shfl_xor(16,32) cross-quarter reduce, quarter-0 writes the tile row.
// VGPR capped (launch_bounds 1024,8) to keep 2 blocks/CU. Rest = R12.

constexpr int NN = 50000;
constexpr int NE = 800000;
constexpr int D  = 128;

constexpr int BS   = 128;                      // nodes per bucket
constexpr int NB   = (NN + BS - 1) / BS;       // 391 buckets
constexpr int EPB  = 4096;                     // edges per producer block
constexpr int NSB  = (NE + EPB - 1) / EPB;     // 196 producer blocks
constexpr int CAP  = 4096;                     // per-bucket LDS edge cap

constexpr int AROWU = 136;                     // tile row stride (ushorts)

typedef __attribute__((ext_vector_type(8))) short bf16x8;
typedef __attribute__((ext_vector_type(4))) float f32x4;

__device__ inline unsigned short f2bf(float f) {           // RNE
    unsigned u = __float_as_uint(f);
    return (unsigned short)((u + 0x7fffu + ((u >> 16) & 1u)) >> 16);
}
__device__ inline float bflo(unsigned v) { return __uint_as_float(v << 16); }
__device__ inline float bfhi(unsigned v) { return __uint_as_float(v & 0xffff0000u); }

// ---- 1. fused prep (bf16 cvt) + bucket-sort partition (R12-verified) ------
constexpr int NF4 = NN * D / 4;                           // 1,600,000
constexpr int W4  = D * D / 4;                            // 4,096
constexpr int NBLK_P = (NF4 + W4 + 511) / 512;            // 3134
constexpr int GRID_A = NSB + NBLK_P;

__global__ __launch_bounds__(512) void k_prep_bucket(
    const float* __restrict__ nf, const float* __restrict__ W,
    const int* __restrict__ ei,
    ushort* __restrict__ nfh, ushort* __restrict__ Wh,
    ushort* __restrict__ offs, unsigned* __restrict__ buf)
{
    __shared__ int hist[NB], off[NB], cur[NB];     // 4692 B
    __shared__ unsigned spk[EPB];                  // 16384 B
    const int t = threadIdx.x;

    if (blockIdx.x < NSB) {
        const int blk = blockIdx.x;
        const int e0  = blk * EPB;
        int cnt = NE - e0; if (cnt > EPB) cnt = EPB;

        for (int i = t; i < NB; i += 512) hist[i] = 0;
        __syncthreads();

        unsigned pk[8];
        #pragma unroll
        for (int j = 0; j < 8; ++j) {
            int idx = j * 512 + t;
            if (idx < cnt) {
                int e = e0 + idx;
                unsigned s = (unsigned)ei[e];
                unsigned d = (unsigned)ei[NE + e];
                pk[j] = (d << 16) | s;             // bucket = pk >> 23
                atomicAdd(&hist[pk[j] >> 23], 1);
            }
        }
        __syncthreads();
        if (t < NB) off[t] = hist[t];
        __syncthreads();
        for (int o = 1; o < NB; o <<= 1) {         // inclusive scan over 391
            int v = (t >= o && t < NB) ? off[t - o] : 0;
            __syncthreads();
            if (t < NB) off[t] += v;
            __syncthreads();
        }
        if (t < NB) {
            int ex = off[t] - hist[t];
            cur[t] = ex;
            offs[blk * (NB + 1) + t] = (ushort)ex; // coalesced ushort row
        }
        if (t == 0) offs[blk * (NB + 1) + NB] = (ushort)cnt;
        __syncthreads();
        #pragma unroll
        for (int j = 0; j < 8; ++j) {
            int idx = j * 512 + t;
            if (idx < cnt) {
                int l = atomicAdd(&cur[pk[j] >> 23], 1);
                spk[l] = pk[j];
            }
        }
        __syncthreads();
        for (int i = t; i < cnt; i += 512)         // dense coalesced 16KB
            buf[(size_t)blk * EPB + i] = spk[i];
    } else {
        // prep branch: bf16 conversion
        int i = (blockIdx.x - NSB) * 512 + t;
        if (i < NF4) {
            float4 v = ((const float4*)nf)[i];
            ((ushort4*)nfh)[i] = make_ushort4(f2bf(v.x), f2bf(v.y), f2bf(v.z), f2bf(v.w));
        } else if (i < NF4 + W4) {
            int k = i - NF4;
            float4 v = ((const float4*)W)[k];
            ((ushort4*)Wh)[k] = make_ushort4(f2bf(v.x), f2bf(v.y), f2bf(v.z), f2bf(v.w));
        }
    }
}

// ---- 2. fused gather-sort + aggregate + linear ----------------------------
__global__ __launch_bounds__(1024, 8) void k_sort_agg(
    const unsigned* __restrict__ nfh, const unsigned* __restrict__ buf,
    const ushort* __restrict__ offs, const ushort* __restrict__ Wh,
    const float* __restrict__ bias, float* __restrict__ out)
{
    __shared__ unsigned pkbuf[CAP];                 // 16384 B
    __shared__ ushort srt[CAP];                     // 8192 B
    __shared__ int scnt[256];                       // 1024 B
    __shared__ int sbase[NSB], rbase[NSB];          // 1568 B
    __shared__ int hist[BS], off[BS], cur[BS];      // 1536 B
    __shared__ __align__(16) unsigned tile[BS * AROWU / 2];  // 34816 B (~63.5KB)
    const int b = blockIdx.x, t = threadIdx.x;
    const int lane = t & 63, w = t >> 6;

    // --- Phase A1: per-producer run bases/counts -> inclusive scan
    int my = 0;
    if (t < NSB) {
        int o0 = (int)offs[t * (NB + 1) + b];
        int o1 = (int)offs[t * (NB + 1) + b + 1];
        rbase[t] = o0;
        my = o1 - o0;
    }
    if (t < 256) scnt[t] = (t < NSB) ? my : 0;
    if (t < BS) hist[t] = 0;
    __syncthreads();
    for (int o = 1; o < 256; o <<= 1) {
        int v = (t >= o && t < 256) ? scnt[t - o] : 0;
        __syncthreads();
        if (t < 256) scnt[t] += v;
        __syncthreads();
    }
    if (t < NSB) sbase[t] = scnt[t] - my;
    __syncthreads();
    int total = scnt[NSB - 1];
    if (total > CAP) total = CAP;                  // defensive

    // --- Phase A2: copy runs into LDS + node histogram
    for (int p = t; p < total; p += 1024) {
        int lo = 0, hi = NSB - 1;                  // min i: scnt[i] > p
        while (lo < hi) {
            int mid = (lo + hi) >> 1;
            if (scnt[mid] > p) hi = mid; else lo = mid + 1;
        }
        unsigned pk = buf[(size_t)lo * EPB + rbase[lo] + (p - sbase[lo])];
        pkbuf[p] = pk;
        atomicAdd(&hist[(pk >> 16) & (BS - 1)], 1);
    }
    __syncthreads();

    // --- Phase A3: node scan + scatter into srt (local CSR)
    if (t < BS) off[t] = hist[t];
    __syncthreads();
    for (int o = 1; o < BS; o <<= 1) {
        int v = (t >= o && t < BS) ? off[t - o] : 0;
        __syncthreads();
        if (t < BS) off[t] += v;
        __syncthreads();
    }
    if (t < BS) { int ex = off[t] - hist[t]; off[t] = ex; cur[t] = ex; }
    __syncthreads();
    for (int e = t; e < total; e += 1024) {
        unsigned pk = pkbuf[e];
        int n = (pk >> 16) & (BS - 1);
        int p = atomicAdd(&cur[n], 1);
        srt[p] = (ushort)(pk & 0xffffu);
    }
    __syncthreads();

    // --- Phase B: dwordx4 gather, 4 edges/instruction, 8 nodes per wave
    const int qq = lane >> 4;                      // quarter: which edge of 4
    const int sl = lane & 15;                      // 16B slot within row
    const uint4* nfv = (const uint4*)nfh;          // row = idx*16 uint4s

    #pragma unroll 1
    for (int i = 0; i < 8; ++i) {
        const int n = w * 8 + i;
        const int beg = off[n], e = beg + hist[n];
        float accA[8] = {0,0,0,0,0,0,0,0};
        float accB[8] = {0,0,0,0,0,0,0,0};
        for (int p = beg; p < e; p += 16) {        // 16 edges, 4 loads in flight
            const int lim = e - 1;
            uint4 v[4];
            #pragma unroll
            for (int j = 0; j < 4; ++j) {
                int pos = p + 4 * j + qq;
                bool ok = pos <= lim;
                if (!ok) pos = lim;                // clamp (valid, L1-warm)
                int s = srt[pos];                  // 4 distinct: 4-way bcast
                uint4 val = nfv[(size_t)s * 16 + sl];
                v[j].x = ok ? val.x : 0u;
                v[j].y = ok ? val.y : 0u;
                v[j].z = ok ? val.z : 0u;
                v[j].w = ok ? val.w : 0u;
            }
            #pragma unroll
            for (int j = 0; j < 4; ++j) {
                float* A = (j & 1) ? accB : accA;
                A[0] += bflo(v[j].x); A[1] += bfhi(v[j].x);
                A[2] += bflo(v[j].y); A[3] += bfhi(v[j].y);
                A[4] += bflo(v[j].z); A[5] += bfhi(v[j].z);
                A[6] += bflo(v[j].w); A[7] += bfhi(v[j].w);
            }
        }
        // cross-quarter butterfly: lanes {l, l^16, l^32, l^48} hold same dims
        float r[8];
        #pragma unroll
        for (int k = 0; k < 8; ++k) {
            float x = accA[k] + accB[k];
            x += __shfl_xor(x, 16);
            x += __shfl_xor(x, 32);
            r[k] = x;
        }
        if (qq == 0) {                             // 16 lanes write 256B row
            uint4 o;
            o.x = (unsigned)f2bf(r[0]) | ((unsigned)f2bf(r[1]) << 16);
            o.y = (unsigned)f2bf(r[2]) | ((unsigned)f2bf(r[3]) << 16);
            o.z = (unsigned)f2bf(r[4]) | ((unsigned)f2bf(r[5]) << 16);
            o.w = (unsigned)f2bf(r[6]) | ((unsigned)f2bf(r[7]) << 16);
            *(uint4*)(tile + n * (AROWU / 2) + sl * 4) = o;
        }
    }
    __syncthreads();

    // --- Phase C: 8 tiles x 8 col-chunks = 64 MFMA tasks over 16 waves
    const int m = lane & 15, q = lane >> 4;
    const ushort* lds = (const ushort*)tile;
    #pragma unroll
    for (int i = 0; i < 4; ++i) {
        const int task = w + 16 * i;                // 0..63, bijective
        const int t16  = task >> 3;                 // row-tile 0..7
        const int c0   = (task & 7) * 16;           // col chunk
        const int grow0 = b * BS + t16 * 16;
        if (grow0 < NN) {                           // last bucket: 5 full tiles
            bf16x8 a[4];
            const ushort* arow = lds + (t16 * 16 + m) * AROWU + q * 8;
            #pragma unroll
            for (int kk = 0; kk < 4; ++kk)
                a[kk] = *(const bf16x8*)(arow + kk * 32);
            float bv = bias[c0 + m];
            f32x4 acc = { bv, bv, bv, bv };
            const ushort* wrow = Wh + (size_t)(c0 + m) * D + q * 8;
            #pragma unroll
            for (int kk = 0; kk < 4; ++kk) {
                bf16x8 bb = *(const bf16x8*)(wrow + kk * 32);
                acc = __builtin_amdgcn_mfma_f32_16x16x32_bf16(a[kk], bb, acc, 0, 0, 0);
            }
            float* op = out + (size_t)(grow0 + q * 4) * D + c0 + m;
            op[0]     = acc[0];
            op[D]     = acc[1];
            op[2 * D] = acc[2];
            op[3 * D] = acc[3];
        }
    }
}

extern "C" void kernel_launch(void* const* d_in, const int* in_sizes, int n_in,
                              void* d_out, int out_size, void* d_ws, size_t ws_size,
                              hipStream_t stream) {
    const float* nf = (const float*)d_in[0];
    const int*   ei = (const int*)d_in[1];
    const float* W  = (const float*)d_in[2];
    const float* b  = (const float*)d_in[3];
    float* out = (float*)d_out;

    // workspace (~16.2 MB)
    ushort*   nfh  = (ushort*)d_ws;                    // NN*D bf16 = 12.8 MB
    ushort*   Wh   = nfh + (size_t)NN * D;             // 32 KB
    unsigned* buf  = (unsigned*)(Wh + D * D);          // NSB*EPB u32 = 3.2 MB
    ushort*   offs = (ushort*)(buf + (size_t)NSB * EPB); // NSB*(NB+1) = 154 KB

    k_prep_bucket<<<GRID_A, 512, 0, stream>>>(nf, W, ei, nfh, Wh, offs, buf);
    k_sort_agg   <<<NB, 1024, 0, stream>>>((const unsigned*)nfh, buf, offs, Wh, b, out);
}